// Round 8
// baseline (247.942 us; speedup 1.0000x reference)
//
#include <hip/hip_runtime.h>
#include <hip/hip_fp16.h>

#define N_NODES 50000
#define N_EDGES 1250000
#define NGRAPH  64
#define NPART   400                        // partitions for CSR build
#define PSIZE   125                        // nodes per partition (400*125 = 50000 exact)
#define CAP     4096                       // bucket capacity per partition (mean 3125, sigma 56 -> +17 sigma)
#define NB      32                         // nodes per block in fused kernels (8 lanes/node)
#define NBLK    ((N_NODES + NB - 1) / NB)  // 1563

struct alignas(16) h8 { __half2 a, b, c, d; };  // 8 fp16 features, one 16-byte load

typedef _Float16 half2v __attribute__((ext_vector_type(2)));
#if __has_builtin(__builtin_amdgcn_fdot2)
__device__ inline float dot2acc(__half2 a, __half2 b, float c) {
    return __builtin_amdgcn_fdot2(__builtin_bit_cast(half2v, a),
                                  __builtin_bit_cast(half2v, b), c, false);
}
#else
__device__ inline float dot2acc(__half2 a, __half2 b, float c) {
    float2 fa = __half22float2(a), fb = __half22float2(b);
    return c + fa.x * fb.x + fa.y * fb.y;
}
#endif

#define ACC8(v)  { float2 fa = __half22float2((v).a), fb = __half22float2((v).b),  \
                          fc = __half22float2((v).c), fd = __half22float2((v).d);  \
                   a0 += fa.x; a1 += fa.y; a2 += fb.x; a3 += fb.y;                 \
                   a4 += fc.x; a5 += fc.y; a6 += fd.x; a7 += fd.y; }

// 8-deep software-pipelined gather over one node's CSR row (8 lanes/node, h8 fp16 loads)
#define GATHER_ROW()                                                                    \
    {                                                                                   \
        int e = beg;                                                                    \
        int s0 = 0, s1 = 0, s2 = 0, s3 = 0, s4 = 0, s5 = 0, s6 = 0, s7 = 0;             \
        bool have = (e + 8 <= end);                                                     \
        if (have) { s0 = csr_src[e];     s1 = csr_src[e + 1]; s2 = csr_src[e + 2];      \
                    s3 = csr_src[e + 3]; s4 = csr_src[e + 4]; s5 = csr_src[e + 5];      \
                    s6 = csr_src[e + 6]; s7 = csr_src[e + 7]; }                         \
        while (have) {                                                                  \
            int ne = e + 8;                                                             \
            bool nh = (ne + 8 <= end);                                                  \
            int t0 = 0, t1 = 0, t2 = 0, t3 = 0, t4 = 0, t5 = 0, t6 = 0, t7 = 0;         \
            if (nh) { t0 = csr_src[ne];     t1 = csr_src[ne + 1]; t2 = csr_src[ne + 2]; \
                      t3 = csr_src[ne + 3]; t4 = csr_src[ne + 4]; t5 = csr_src[ne + 5]; \
                      t6 = csr_src[ne + 6]; t7 = csr_src[ne + 7]; }                     \
            h8 v0 = *(const h8*)(xbase + s0 * 64);                                      \
            h8 v1 = *(const h8*)(xbase + s1 * 64);                                      \
            h8 v2 = *(const h8*)(xbase + s2 * 64);                                      \
            h8 v3 = *(const h8*)(xbase + s3 * 64);                                      \
            h8 v4 = *(const h8*)(xbase + s4 * 64);                                      \
            h8 v5 = *(const h8*)(xbase + s5 * 64);                                      \
            h8 v6 = *(const h8*)(xbase + s6 * 64);                                      \
            h8 v7 = *(const h8*)(xbase + s7 * 64);                                      \
            ACC8(v0); ACC8(v1); ACC8(v2); ACC8(v3);                                     \
            ACC8(v4); ACC8(v5); ACC8(v6); ACC8(v7);                                     \
            s0 = t0; s1 = t1; s2 = t2; s3 = t3;                                         \
            s4 = t4; s5 = t5; s6 = t6; s7 = t7;                                         \
            e = ne; have = nh;                                                          \
        }                                                                               \
        if (e + 4 <= end) {                                                             \
            int q0 = csr_src[e], q1 = csr_src[e + 1], q2 = csr_src[e + 2],              \
                q3 = csr_src[e + 3];                                                    \
            h8 v0 = *(const h8*)(xbase + q0 * 64);                                      \
            h8 v1 = *(const h8*)(xbase + q1 * 64);                                      \
            h8 v2 = *(const h8*)(xbase + q2 * 64);                                      \
            h8 v3 = *(const h8*)(xbase + q3 * 64);                                      \
            ACC8(v0); ACC8(v1); ACC8(v2); ACC8(v3);                                     \
            e += 4;                                                                     \
        }                                                                               \
        for (; e < end; ++e) {                                                          \
            int s = csr_src[e];                                                         \
            h8 v = *(const h8*)(xbase + s * 64);                                        \
            ACC8(v);                                                                    \
        }                                                                               \
    }

// ---------------------------------------------------------------- bucket edges by partition (int4 edge reads)
__global__ void bucket_kernel(const int* __restrict__ ei, int* __restrict__ pcount,
                              int* __restrict__ bucket) {
    __shared__ int hist[NPART];
    __shared__ int sbase[NPART];
    int tid = threadIdx.x;
    for (int i = tid; i < NPART; i += 256) hist[i] = 0;
    __syncthreads();
    int gtid = blockIdx.x * 256 + tid;
    int gstr = gridDim.x * 256;
    for (int e4 = gtid * 4; e4 < N_EDGES; e4 += gstr * 4) {   // E divisible by 4
        int4 d = *(const int4*)(ei + N_EDGES + e4);
        atomicAdd(&hist[d.x / PSIZE], 1);
        atomicAdd(&hist[d.y / PSIZE], 1);
        atomicAdd(&hist[d.z / PSIZE], 1);
        atomicAdd(&hist[d.w / PSIZE], 1);
    }
    __syncthreads();
    for (int i = tid; i < NPART; i += 256) {
        sbase[i] = hist[i] ? atomicAdd(&pcount[i], hist[i]) : 0;
        hist[i] = 0;   // reuse as local offset
    }
    __syncthreads();
    for (int e4 = gtid * 4; e4 < N_EDGES; e4 += gstr * 4) {
        int4 d = *(const int4*)(ei + N_EDGES + e4);
        int4 s = *(const int4*)(ei + e4);
        int p0 = d.x / PSIZE; int l0 = atomicAdd(&hist[p0], 1);
        bucket[p0 * CAP + sbase[p0] + l0] = (s.x << 8) | (d.x - p0 * PSIZE);
        int p1 = d.y / PSIZE; int l1 = atomicAdd(&hist[p1], 1);
        bucket[p1 * CAP + sbase[p1] + l1] = (s.y << 8) | (d.y - p1 * PSIZE);
        int p2 = d.z / PSIZE; int l2 = atomicAdd(&hist[p2], 1);
        bucket[p2 * CAP + sbase[p2] + l2] = (s.z << 8) | (d.z - p2 * PSIZE);
        int p3 = d.w / PSIZE; int l3 = atomicAdd(&hist[p3], 1);
        bucket[p3 * CAP + sbase[p3] + l3] = (s.w << 8) | (d.w - p3 * PSIZE);
    }
}

// ---------------------------------------------------------------- per-partition deg+scan+rows+dinv+fill (+graph node counts)
__global__ void csr_kernel(const int* __restrict__ pcount, const int* __restrict__ bucket,
                           const int* __restrict__ batch,
                           int* __restrict__ row_beg, int* __restrict__ row_end,
                           float* __restrict__ dinv, int* __restrict__ csr_src,
                           float* __restrict__ cnt) {
    __shared__ int hist[256];
    __shared__ int s[256];
    __shared__ int cur[128];
    __shared__ int ghist[64];
    int p = blockIdx.x;
    int tid = threadIdx.x;
    int base = p * CAP;
    int cntE = min(pcount[p], CAP);
    hist[tid] = 0;
    __syncthreads();
    for (int e = tid; e < cntE; e += 256)
        atomicAdd(&hist[bucket[base + e] & 0xFF], 1);
    __syncthreads();
    int v = (tid < PSIZE) ? hist[tid] : 0;
    s[tid] = v;
    __syncthreads();
    for (int off = 1; off < 256; off <<= 1) {
        int t = (tid >= off) ? s[tid - off] : 0;
        __syncthreads();
        s[tid] += t;
        __syncthreads();
    }
    if (tid < PSIZE) {
        int ex = s[tid] - v;
        int node = p * PSIZE + tid;
        row_beg[node] = base + ex;
        row_end[node] = base + ex + v;
        dinv[node] = rsqrtf((float)v + 1.0f);   // +1 self-loop
        cur[tid] = ex;
    }
    __syncthreads();
    for (int e = tid; e < cntE; e += 256) {
        int pk = bucket[base + e];
        int l = atomicAdd(&cur[pk & 0xFF], 1);
        csr_src[base + l] = pk >> 8;
    }
    if (tid < 64) ghist[tid] = 0;
    __syncthreads();
    if (tid < PSIZE) atomicAdd(&ghist[batch[p * PSIZE + tid]], 1);
    __syncthreads();
    if (tid < 64 && ghist[tid]) atomicAdd(&cnt[tid], (float)ghist[tid]);
}

// ---------------------------------------------------------------- layer-0 GEMM (fp32 x) -> dinv-scaled fp16
__global__ void gemm64_kernel(const float* __restrict__ h, const float* __restrict__ W,
                              const float* __restrict__ dinv, __half* __restrict__ out) {
    __shared__ alignas(16) __half2 hs2[256];   // 8 rows x 32 half2
    int tid = threadIdx.x;
    int tx = tid & 63;
    int r0 = (tid >> 6) * 2;
    __half2 wcol2[32];
#pragma unroll
    for (int k2 = 0; k2 < 32; ++k2)
        wcol2[k2] = __floats2half2_rn(W[(2 * k2) * 64 + tx], W[(2 * k2 + 1) * 64 + tx]);
    const int nchunks = N_NODES / 8;  // 6250
    for (int grp = blockIdx.x; grp < nchunks; grp += gridDim.x) {
        __syncthreads();
        float2 xv = ((const float2*)(h + grp * 512))[tid];
        hs2[tid] = __floats2half2_rn(xv.x, xv.y);
        __syncthreads();
        float acc0 = 0.f, acc1 = 0.f;
        const h8* row0 = (const h8*)&hs2[r0 * 32];
        const h8* row1 = (const h8*)&hs2[(r0 + 1) * 32];
#pragma unroll
        for (int j = 0; j < 8; ++j) {
            h8 v0 = row0[j];
            h8 v1 = row1[j];
            acc0 = dot2acc(v0.a, wcol2[4 * j + 0], acc0);
            acc0 = dot2acc(v0.b, wcol2[4 * j + 1], acc0);
            acc0 = dot2acc(v0.c, wcol2[4 * j + 2], acc0);
            acc0 = dot2acc(v0.d, wcol2[4 * j + 3], acc0);
            acc1 = dot2acc(v1.a, wcol2[4 * j + 0], acc1);
            acc1 = dot2acc(v1.b, wcol2[4 * j + 1], acc1);
            acc1 = dot2acc(v1.c, wcol2[4 * j + 2], acc1);
            acc1 = dot2acc(v1.d, wcol2[4 * j + 3], acc1);
        }
        int nbase = grp * 8 + r0;
        out[nbase * 64 + tx]       = __float2half(acc0 * dinv[nbase]);
        out[(nbase + 1) * 64 + tx] = __float2half(acc1 * dinv[nbase + 1]);
    }
}

// ---------------------------------------------------------------- fused gather + relu + next-layer GEMM
// 8 lanes/node, 32 nodes/block, 8-deep pipelined h8 gathers.
// GEMM phase: lane = output column, W in 32 half2 regs, fdot2 over broadcast LDS rows.
__global__ void fused_layer_kernel(const int* __restrict__ row_beg, const int* __restrict__ row_end,
                                   const int* __restrict__ csr_src, const float* __restrict__ dinv,
                                   const __half* __restrict__ xin, const float* __restrict__ b,
                                   const float* __restrict__ Wn, __half* __restrict__ xout) {
    __shared__ alignas(16) __half2 hs16[NB][32];  // 32 rows x 64 fp16 features
    __shared__ float sdinv[NB];
    int tid = threadIdx.x;
    int nl  = tid >> 3;          // local node 0..31
    int l8  = tid & 7;           // feature octet
    int node = blockIdx.x * NB + nl;
    bool valid = node < N_NODES;
    float a0 = 0.f, a1 = 0.f, a2 = 0.f, a3 = 0.f, a4 = 0.f, a5 = 0.f, a6 = 0.f, a7 = 0.f;
    const __half* xbase = xin + 8 * l8;
    if (valid) {
        int beg = row_beg[node];
        int end = row_end[node];
        GATHER_ROW();
        float d = dinv[node];
        h8 sv = *(const h8*)(xbase + node * 64);
        float2 sa = __half22float2(sv.a), sb2 = __half22float2(sv.b);
        float2 sc = __half22float2(sv.c), sd2 = __half22float2(sv.d);
        const float4 bb0 = *(const float4*)(b + 8 * l8);
        const float4 bb1 = *(const float4*)(b + 8 * l8 + 4);
        float v0 = fmaxf(d * (a0 + sa.x)  + bb0.x, 0.f);
        float v1 = fmaxf(d * (a1 + sa.y)  + bb0.y, 0.f);
        float v2 = fmaxf(d * (a2 + sb2.x) + bb0.z, 0.f);
        float v3 = fmaxf(d * (a3 + sb2.y) + bb0.w, 0.f);
        float v4 = fmaxf(d * (a4 + sc.x)  + bb1.x, 0.f);
        float v5 = fmaxf(d * (a5 + sc.y)  + bb1.y, 0.f);
        float v6 = fmaxf(d * (a6 + sd2.x) + bb1.z, 0.f);
        float v7 = fmaxf(d * (a7 + sd2.y) + bb1.w, 0.f);
        h8 o;
        o.a = __float22half2_rn(make_float2(v0, v1));
        o.b = __float22half2_rn(make_float2(v2, v3));
        o.c = __float22half2_rn(make_float2(v4, v5));
        o.d = __float22half2_rn(make_float2(v6, v7));
        ((h8*)&hs16[nl][0])[l8] = o;
        if (l8 == 0) sdinv[nl] = d;
    }
    __syncthreads();
    // ---- GEMM phase: wave wv handles rows wv*8..wv*8+7, lane tx = output column
    int tx = tid & 63;
    int wv = tid >> 6;
    __half2 wcol2[32];
#pragma unroll
    for (int k2 = 0; k2 < 32; ++k2)
        wcol2[k2] = __floats2half2_rn(Wn[(2 * k2) * 64 + tx], Wn[(2 * k2 + 1) * 64 + tx]);
    int rbase = blockIdx.x * NB;
#pragma unroll
    for (int rr = 0; rr < 8; ++rr) {
        int r = wv * 8 + rr;
        int n2 = rbase + r;
        if (n2 >= N_NODES) break;
        const h8* row = (const h8*)&hs16[r][0];
        float acc = 0.f;
#pragma unroll
        for (int j = 0; j < 8; ++j) {
            h8 v = row[j];
            acc = dot2acc(v.a, wcol2[4 * j + 0], acc);
            acc = dot2acc(v.b, wcol2[4 * j + 1], acc);
            acc = dot2acc(v.c, wcol2[4 * j + 2], acc);
            acc = dot2acc(v.d, wcol2[4 * j + 3], acc);
        }
        xout[n2 * 64 + tx] = __float2half(acc * sdinv[r]);
    }
}

// ---------------------------------------------------------------- fused final gather (no relu) + pooling + head
// Last block to retire (device-scope counter) computes the head in-kernel.
__global__ void gather_pool_kernel(const int* __restrict__ row_beg, const int* __restrict__ row_end,
                                   const int* __restrict__ csr_src, const float* __restrict__ dinv,
                                   const __half* __restrict__ xin, const float* __restrict__ b,
                                   const int* __restrict__ batch, float* __restrict__ pool,
                                   float* __restrict__ cnt, const float* __restrict__ Wp,
                                   const float* __restrict__ bp, float* __restrict__ out,
                                   int* __restrict__ done) {
    __shared__ alignas(16) float hsf[NB][64];
    __shared__ int sg[NB];
    __shared__ int allsame;
    __shared__ int lastflag;
    int tid = threadIdx.x;
    int nl  = tid >> 3;
    int l8  = tid & 7;
    int node = blockIdx.x * NB + nl;
    bool valid = node < N_NODES;
    float a0 = 0.f, a1 = 0.f, a2 = 0.f, a3 = 0.f, a4 = 0.f, a5 = 0.f, a6 = 0.f, a7 = 0.f;
    const __half* xbase = xin + 8 * l8;
    float v0 = 0.f, v1 = 0.f, v2 = 0.f, v3 = 0.f, v4 = 0.f, v5 = 0.f, v6 = 0.f, v7 = 0.f;
    if (valid) {
        int beg = row_beg[node];
        int end = row_end[node];
        GATHER_ROW();
        float d = dinv[node];
        h8 sv = *(const h8*)(xbase + node * 64);
        float2 sa = __half22float2(sv.a), sb2 = __half22float2(sv.b);
        float2 sc = __half22float2(sv.c), sd2 = __half22float2(sv.d);
        const float4 bb0 = *(const float4*)(b + 8 * l8);
        const float4 bb1 = *(const float4*)(b + 8 * l8 + 4);
        v0 = d * (a0 + sa.x)  + bb0.x;   // no relu on last layer
        v1 = d * (a1 + sa.y)  + bb0.y;
        v2 = d * (a2 + sb2.x) + bb0.z;
        v3 = d * (a3 + sb2.y) + bb0.w;
        v4 = d * (a4 + sc.x)  + bb1.x;
        v5 = d * (a5 + sc.y)  + bb1.y;
        v6 = d * (a6 + sd2.x) + bb1.z;
        v7 = d * (a7 + sd2.y) + bb1.w;
    }
    if (l8 == 0) sg[nl] = batch[valid ? node : (N_NODES - 1)];
    if (tid == 0) allsame = 1;
    *(float4*)&hsf[nl][8 * l8]     = make_float4(v0, v1, v2, v3);
    *(float4*)&hsf[nl][8 * l8 + 4] = make_float4(v4, v5, v6, v7);
    __syncthreads();
    if (tid < NB && sg[tid] != sg[0]) allsame = 0;   // benign race, all writes = 0
    __syncthreads();
    if (allsame) {
        if (tid < 64) {
            float s = 0.f;
#pragma unroll
            for (int n = 0; n < NB; ++n) s += hsf[n][tid];
            atomicAdd(&pool[sg[0] * 64 + tid], s);
        }
    } else if (valid) {
        int g = sg[nl];
        atomicAdd(&pool[g * 64 + 8 * l8 + 0], v0);
        atomicAdd(&pool[g * 64 + 8 * l8 + 1], v1);
        atomicAdd(&pool[g * 64 + 8 * l8 + 2], v2);
        atomicAdd(&pool[g * 64 + 8 * l8 + 3], v3);
        atomicAdd(&pool[g * 64 + 8 * l8 + 4], v4);
        atomicAdd(&pool[g * 64 + 8 * l8 + 5], v5);
        atomicAdd(&pool[g * 64 + 8 * l8 + 6], v6);
        atomicAdd(&pool[g * 64 + 8 * l8 + 7], v7);
    }
    // ---- retirement: last block computes the head (agent-scope loads bypass stale L2)
    __syncthreads();
    if (tid == 0) {
        __threadfence();
        lastflag = (atomicAdd(done, 1) == (int)gridDim.x - 1);
    }
    __syncthreads();
    if (lastflag) {
        int lane = tid & 63;
        int wv = tid >> 6;
#pragma unroll
        for (int gi = 0; gi < NGRAPH / 4; ++gi) {
            int g = wv * (NGRAPH / 4) + gi;
            float v = __hip_atomic_load(&pool[g * 64 + lane], __ATOMIC_RELAXED,
                                        __HIP_MEMORY_SCOPE_AGENT) * Wp[lane];
#pragma unroll
            for (int off = 32; off > 0; off >>= 1) v += __shfl_down(v, off);
            if (lane == 0) {
                float c = __hip_atomic_load(&cnt[g], __ATOMIC_RELAXED,
                                            __HIP_MEMORY_SCOPE_AGENT);
                out[g] = v / fmaxf(c, 1.0f) + bp[0];
            }
        }
    }
}

extern "C" void kernel_launch(void* const* d_in, const int* in_sizes, int n_in,
                              void* d_out, int out_size, void* d_ws, size_t ws_size,
                              hipStream_t stream) {
    const float* x     = (const float*)d_in[0];
    const int*   ei    = (const int*)d_in[1];
    const int*   batch = (const int*)d_in[2];
    const float* W0 = (const float*)d_in[3];
    const float* b0 = (const float*)d_in[4];
    const float* W1 = (const float*)d_in[5];
    const float* b1 = (const float*)d_in[6];
    const float* W2 = (const float*)d_in[7];
    const float* b2 = (const float*)d_in[8];
    const float* Wp = (const float*)d_in[9];
    const float* bp = (const float*)d_in[10];
    float* out = (float*)d_out;

    __half* xws  = (__half*)d_ws;                      // N*64 fp16 (ping)
    __half* xwsB = xws + N_NODES * 64;                 // N*64 fp16 (pong)
    float* dinv    = (float*)(xwsB + N_NODES * 64);    // N
    int*   row_beg = (int*)(dinv + N_NODES);           // N
    int*   row_end = row_beg + N_NODES;                // N
    int*   csr_src = row_end + N_NODES;                // NPART*CAP
    int*   bucket  = csr_src + NPART * CAP;            // NPART*CAP
    int*   pcount  = bucket + NPART * CAP;             // NPART (contiguous with pool+cnt+done)
    float* pool    = (float*)(pcount + NPART);         // 64*64
    float* cnt     = pool + 64 * 64;                   // 64
    int*   done    = (int*)(cnt + 64);                 // 1

    // single fused zero-fill: pcount + pool + cnt + done are contiguous
    (void)hipMemsetAsync(pcount, 0, (NPART + 64 * 64 + 64 + 1) * sizeof(int), stream);

    // ---- CSR build
    bucket_kernel<<<512, 256, 0, stream>>>(ei, pcount, bucket);
    csr_kernel<<<NPART, 256, 0, stream>>>(pcount, bucket, batch, row_beg, row_end, dinv,
                                          csr_src, cnt);

    // ---- layer 0 transform (fp32 input x) -> fp16
    gemm64_kernel<<<1024, 256, 0, stream>>>(x, W0, dinv, xws);
    // ---- fused: layer-0 aggregate + relu + layer-1 transform
    fused_layer_kernel<<<NBLK, 256, 0, stream>>>(row_beg, row_end, csr_src, dinv,
                                                 xws, b0, W1, xwsB);
    // ---- fused: layer-1 aggregate + relu + layer-2 transform
    fused_layer_kernel<<<NBLK, 256, 0, stream>>>(row_beg, row_end, csr_src, dinv,
                                                 xwsB, b1, W2, xws);
    // ---- fused: layer-2 aggregate (no relu) + pool + head (last block)
    gather_pool_kernel<<<NBLK, 256, 0, stream>>>(row_beg, row_end, csr_src, dinv,
                                                 xws, b2, batch, pool, cnt, Wp, bp,
                                                 out, done);
}

// Round 9
// 210.139 us; speedup vs baseline: 1.1799x; 1.1799x over previous
//
#include <hip/hip_runtime.h>
#include <hip/hip_fp16.h>

#define N_NODES 50000
#define N_EDGES 1250000
#define NGRAPH  64
#define NPART   400                        // partitions for CSR build
#define PSIZE   125                        // nodes per partition (400*125 = 50000 exact)
#define CAP     4096                       // bucket capacity per partition (mean 3125, sigma 56 -> +17 sigma)
#define NB      32                         // nodes per block in fused kernels (8 lanes/node)
#define NBLK    ((N_NODES + NB - 1) / NB)  // 1563

struct alignas(16) h8 { __half2 a, b, c, d; };  // 8 fp16 features, one 16-byte load

typedef _Float16 half2v __attribute__((ext_vector_type(2)));
#if __has_builtin(__builtin_amdgcn_fdot2)
__device__ inline float dot2acc(__half2 a, __half2 b, float c) {
    return __builtin_amdgcn_fdot2(__builtin_bit_cast(half2v, a),
                                  __builtin_bit_cast(half2v, b), c, false);
}
#else
__device__ inline float dot2acc(__half2 a, __half2 b, float c) {
    float2 fa = __half22float2(a), fb = __half22float2(b);
    return c + fa.x * fb.x + fa.y * fb.y;
}
#endif

#define ACC8(v)  { float2 fa = __half22float2((v).a), fb = __half22float2((v).b),  \
                          fc = __half22float2((v).c), fd = __half22float2((v).d);  \
                   a0 += fa.x; a1 += fa.y; a2 += fb.x; a3 += fb.y;                 \
                   a4 += fc.x; a5 += fc.y; a6 += fd.x; a7 += fd.y; }

// 4-deep software-pipelined gather over one node's CSR row (8 lanes/node, h8 loads,
// uint16 CSR indices). Round-3 proven depth; 8-deep was within noise (r5 A/B).
#define GATHER_ROW()                                                                    \
    {                                                                                   \
        int e = beg;                                                                    \
        int s0 = 0, s1 = 0, s2 = 0, s3 = 0;                                             \
        bool have = (e + 4 <= end);                                                     \
        if (have) { s0 = csr_src[e];     s1 = csr_src[e + 1];                           \
                    s2 = csr_src[e + 2]; s3 = csr_src[e + 3]; }                         \
        while (have) {                                                                  \
            int ne = e + 4;                                                             \
            bool nh = (ne + 4 <= end);                                                  \
            int t0 = 0, t1 = 0, t2 = 0, t3 = 0;                                         \
            if (nh) { t0 = csr_src[ne];     t1 = csr_src[ne + 1];                       \
                      t2 = csr_src[ne + 2]; t3 = csr_src[ne + 3]; }                     \
            h8 v0 = *(const h8*)(xbase + s0 * 64);                                      \
            h8 v1 = *(const h8*)(xbase + s1 * 64);                                      \
            h8 v2 = *(const h8*)(xbase + s2 * 64);                                      \
            h8 v3 = *(const h8*)(xbase + s3 * 64);                                      \
            ACC8(v0); ACC8(v1); ACC8(v2); ACC8(v3);                                     \
            s0 = t0; s1 = t1; s2 = t2; s3 = t3;                                         \
            e = ne; have = nh;                                                          \
        }                                                                               \
        for (; e < end; ++e) {                                                          \
            int s = csr_src[e];                                                         \
            h8 v = *(const h8*)(xbase + s * 64);                                        \
            ACC8(v);                                                                    \
        }                                                                               \
    }

// ---------------------------------------------------------------- bucket edges by partition (int4 edge reads)
__global__ void bucket_kernel(const int* __restrict__ ei, int* __restrict__ pcount,
                              int* __restrict__ bucket) {
    __shared__ int hist[NPART];
    __shared__ int sbase[NPART];
    int tid = threadIdx.x;
    for (int i = tid; i < NPART; i += 256) hist[i] = 0;
    __syncthreads();
    int gtid = blockIdx.x * 256 + tid;
    int gstr = gridDim.x * 256;
    for (int e4 = gtid * 4; e4 < N_EDGES; e4 += gstr * 4) {   // E divisible by 4
        int4 d = *(const int4*)(ei + N_EDGES + e4);
        atomicAdd(&hist[d.x / PSIZE], 1);
        atomicAdd(&hist[d.y / PSIZE], 1);
        atomicAdd(&hist[d.z / PSIZE], 1);
        atomicAdd(&hist[d.w / PSIZE], 1);
    }
    __syncthreads();
    for (int i = tid; i < NPART; i += 256) {
        sbase[i] = hist[i] ? atomicAdd(&pcount[i], hist[i]) : 0;
        hist[i] = 0;   // reuse as local offset
    }
    __syncthreads();
    for (int e4 = gtid * 4; e4 < N_EDGES; e4 += gstr * 4) {
        int4 d = *(const int4*)(ei + N_EDGES + e4);
        int4 s = *(const int4*)(ei + e4);
        int p0 = d.x / PSIZE; int l0 = atomicAdd(&hist[p0], 1);
        bucket[p0 * CAP + sbase[p0] + l0] = (s.x << 8) | (d.x - p0 * PSIZE);
        int p1 = d.y / PSIZE; int l1 = atomicAdd(&hist[p1], 1);
        bucket[p1 * CAP + sbase[p1] + l1] = (s.y << 8) | (d.y - p1 * PSIZE);
        int p2 = d.z / PSIZE; int l2 = atomicAdd(&hist[p2], 1);
        bucket[p2 * CAP + sbase[p2] + l2] = (s.z << 8) | (d.z - p2 * PSIZE);
        int p3 = d.w / PSIZE; int l3 = atomicAdd(&hist[p3], 1);
        bucket[p3 * CAP + sbase[p3] + l3] = (s.w << 8) | (d.w - p3 * PSIZE);
    }
}

// ---------------------------------------------------------------- per-partition deg+scan+rows+dinv+fill (+graph node counts)
__global__ void csr_kernel(const int* __restrict__ pcount, const int* __restrict__ bucket,
                           const int* __restrict__ batch,
                           int* __restrict__ row_beg, int* __restrict__ row_end,
                           float* __restrict__ dinv, unsigned short* __restrict__ csr_src,
                           float* __restrict__ cnt) {
    __shared__ int hist[256];
    __shared__ int s[256];
    __shared__ int cur[128];
    __shared__ int ghist[64];
    int p = blockIdx.x;
    int tid = threadIdx.x;
    int base = p * CAP;
    int cntE = min(pcount[p], CAP);
    hist[tid] = 0;
    __syncthreads();
    for (int e = tid; e < cntE; e += 256)
        atomicAdd(&hist[bucket[base + e] & 0xFF], 1);
    __syncthreads();
    int v = (tid < PSIZE) ? hist[tid] : 0;
    s[tid] = v;
    __syncthreads();
    for (int off = 1; off < 256; off <<= 1) {
        int t = (tid >= off) ? s[tid - off] : 0;
        __syncthreads();
        s[tid] += t;
        __syncthreads();
    }
    if (tid < PSIZE) {
        int ex = s[tid] - v;
        int node = p * PSIZE + tid;
        row_beg[node] = base + ex;
        row_end[node] = base + ex + v;
        dinv[node] = rsqrtf((float)v + 1.0f);   // +1 self-loop
        cur[tid] = ex;
    }
    __syncthreads();
    for (int e = tid; e < cntE; e += 256) {
        int pk = bucket[base + e];
        int l = atomicAdd(&cur[pk & 0xFF], 1);
        csr_src[base + l] = (unsigned short)(pk >> 8);   // node index < 50000 < 65536
    }
    if (tid < 64) ghist[tid] = 0;
    __syncthreads();
    if (tid < PSIZE) atomicAdd(&ghist[batch[p * PSIZE + tid]], 1);
    __syncthreads();
    if (tid < 64 && ghist[tid]) atomicAdd(&cnt[tid], (float)ghist[tid]);
}

// ---------------------------------------------------------------- layer-0 GEMM (fp32 x) -> dinv-scaled fp16
__global__ void gemm64_kernel(const float* __restrict__ h, const float* __restrict__ W,
                              const float* __restrict__ dinv, __half* __restrict__ out) {
    __shared__ alignas(16) __half2 hs2[256];   // 8 rows x 32 half2
    int tid = threadIdx.x;
    int tx = tid & 63;
    int r0 = (tid >> 6) * 2;
    __half2 wcol2[32];
#pragma unroll
    for (int k2 = 0; k2 < 32; ++k2)
        wcol2[k2] = __floats2half2_rn(W[(2 * k2) * 64 + tx], W[(2 * k2 + 1) * 64 + tx]);
    const int nchunks = N_NODES / 8;  // 6250
    for (int grp = blockIdx.x; grp < nchunks; grp += gridDim.x) {
        __syncthreads();
        float2 xv = ((const float2*)(h + grp * 512))[tid];
        hs2[tid] = __floats2half2_rn(xv.x, xv.y);
        __syncthreads();
        float acc0 = 0.f, acc1 = 0.f;
        const h8* row0 = (const h8*)&hs2[r0 * 32];
        const h8* row1 = (const h8*)&hs2[(r0 + 1) * 32];
#pragma unroll
        for (int j = 0; j < 8; ++j) {
            h8 v0 = row0[j];
            h8 v1 = row1[j];
            acc0 = dot2acc(v0.a, wcol2[4 * j + 0], acc0);
            acc0 = dot2acc(v0.b, wcol2[4 * j + 1], acc0);
            acc0 = dot2acc(v0.c, wcol2[4 * j + 2], acc0);
            acc0 = dot2acc(v0.d, wcol2[4 * j + 3], acc0);
            acc1 = dot2acc(v1.a, wcol2[4 * j + 0], acc1);
            acc1 = dot2acc(v1.b, wcol2[4 * j + 1], acc1);
            acc1 = dot2acc(v1.c, wcol2[4 * j + 2], acc1);
            acc1 = dot2acc(v1.d, wcol2[4 * j + 3], acc1);
        }
        int nbase = grp * 8 + r0;
        out[nbase * 64 + tx]       = __float2half(acc0 * dinv[nbase]);
        out[(nbase + 1) * 64 + tx] = __float2half(acc1 * dinv[nbase + 1]);
    }
}

// ---------------------------------------------------------------- fused gather + relu + next-layer GEMM
__global__ void fused_layer_kernel(const int* __restrict__ row_beg, const int* __restrict__ row_end,
                                   const unsigned short* __restrict__ csr_src,
                                   const float* __restrict__ dinv,
                                   const __half* __restrict__ xin, const float* __restrict__ b,
                                   const float* __restrict__ Wn, __half* __restrict__ xout) {
    __shared__ alignas(16) __half2 hs16[NB][32];  // 32 rows x 64 fp16 features
    __shared__ float sdinv[NB];
    int tid = threadIdx.x;
    int nl  = tid >> 3;          // local node 0..31
    int l8  = tid & 7;           // feature octet
    int node = blockIdx.x * NB + nl;
    bool valid = node < N_NODES;
    float a0 = 0.f, a1 = 0.f, a2 = 0.f, a3 = 0.f, a4 = 0.f, a5 = 0.f, a6 = 0.f, a7 = 0.f;
    const __half* xbase = xin + 8 * l8;
    if (valid) {
        int beg = row_beg[node];
        int end = row_end[node];
        GATHER_ROW();
        float d = dinv[node];
        h8 sv = *(const h8*)(xbase + node * 64);
        float2 sa = __half22float2(sv.a), sb2 = __half22float2(sv.b);
        float2 sc = __half22float2(sv.c), sd2 = __half22float2(sv.d);
        const float4 bb0 = *(const float4*)(b + 8 * l8);
        const float4 bb1 = *(const float4*)(b + 8 * l8 + 4);
        float v0 = fmaxf(d * (a0 + sa.x)  + bb0.x, 0.f);
        float v1 = fmaxf(d * (a1 + sa.y)  + bb0.y, 0.f);
        float v2 = fmaxf(d * (a2 + sb2.x) + bb0.z, 0.f);
        float v3 = fmaxf(d * (a3 + sb2.y) + bb0.w, 0.f);
        float v4 = fmaxf(d * (a4 + sc.x)  + bb1.x, 0.f);
        float v5 = fmaxf(d * (a5 + sc.y)  + bb1.y, 0.f);
        float v6 = fmaxf(d * (a6 + sd2.x) + bb1.z, 0.f);
        float v7 = fmaxf(d * (a7 + sd2.y) + bb1.w, 0.f);
        h8 o;
        o.a = __float22half2_rn(make_float2(v0, v1));
        o.b = __float22half2_rn(make_float2(v2, v3));
        o.c = __float22half2_rn(make_float2(v4, v5));
        o.d = __float22half2_rn(make_float2(v6, v7));
        ((h8*)&hs16[nl][0])[l8] = o;
        if (l8 == 0) sdinv[nl] = d;
    }
    __syncthreads();
    // ---- GEMM phase: wave wv handles rows wv*8..wv*8+7, lane tx = output column
    int tx = tid & 63;
    int wv = tid >> 6;
    __half2 wcol2[32];
#pragma unroll
    for (int k2 = 0; k2 < 32; ++k2)
        wcol2[k2] = __floats2half2_rn(Wn[(2 * k2) * 64 + tx], Wn[(2 * k2 + 1) * 64 + tx]);
    int rbase = blockIdx.x * NB;
#pragma unroll
    for (int rr = 0; rr < 8; ++rr) {
        int r = wv * 8 + rr;
        int n2 = rbase + r;
        if (n2 >= N_NODES) break;
        const h8* row = (const h8*)&hs16[r][0];
        float acc = 0.f;
#pragma unroll
        for (int j = 0; j < 8; ++j) {
            h8 v = row[j];
            acc = dot2acc(v.a, wcol2[4 * j + 0], acc);
            acc = dot2acc(v.b, wcol2[4 * j + 1], acc);
            acc = dot2acc(v.c, wcol2[4 * j + 2], acc);
            acc = dot2acc(v.d, wcol2[4 * j + 3], acc);
        }
        xout[n2 * 64 + tx] = __float2half(acc * sdinv[r]);
    }
}

// ---------------------------------------------------------------- fused final gather (no relu) + pooling
__global__ void gather_pool_kernel(const int* __restrict__ row_beg, const int* __restrict__ row_end,
                                   const unsigned short* __restrict__ csr_src,
                                   const float* __restrict__ dinv,
                                   const __half* __restrict__ xin, const float* __restrict__ b,
                                   const int* __restrict__ batch, float* __restrict__ pool) {
    __shared__ alignas(16) float hsf[NB][64];
    __shared__ int sg[NB];
    __shared__ int allsame;
    int tid = threadIdx.x;
    int nl  = tid >> 3;
    int l8  = tid & 7;
    int node = blockIdx.x * NB + nl;
    bool valid = node < N_NODES;
    float a0 = 0.f, a1 = 0.f, a2 = 0.f, a3 = 0.f, a4 = 0.f, a5 = 0.f, a6 = 0.f, a7 = 0.f;
    const __half* xbase = xin + 8 * l8;
    float v0 = 0.f, v1 = 0.f, v2 = 0.f, v3 = 0.f, v4 = 0.f, v5 = 0.f, v6 = 0.f, v7 = 0.f;
    if (valid) {
        int beg = row_beg[node];
        int end = row_end[node];
        GATHER_ROW();
        float d = dinv[node];
        h8 sv = *(const h8*)(xbase + node * 64);
        float2 sa = __half22float2(sv.a), sb2 = __half22float2(sv.b);
        float2 sc = __half22float2(sv.c), sd2 = __half22float2(sv.d);
        const float4 bb0 = *(const float4*)(b + 8 * l8);
        const float4 bb1 = *(const float4*)(b + 8 * l8 + 4);
        v0 = d * (a0 + sa.x)  + bb0.x;   // no relu on last layer
        v1 = d * (a1 + sa.y)  + bb0.y;
        v2 = d * (a2 + sb2.x) + bb0.z;
        v3 = d * (a3 + sb2.y) + bb0.w;
        v4 = d * (a4 + sc.x)  + bb1.x;
        v5 = d * (a5 + sc.y)  + bb1.y;
        v6 = d * (a6 + sd2.x) + bb1.z;
        v7 = d * (a7 + sd2.y) + bb1.w;
    }
    if (l8 == 0) sg[nl] = batch[valid ? node : (N_NODES - 1)];
    if (tid == 0) allsame = 1;
    *(float4*)&hsf[nl][8 * l8]     = make_float4(v0, v1, v2, v3);
    *(float4*)&hsf[nl][8 * l8 + 4] = make_float4(v4, v5, v6, v7);
    __syncthreads();
    if (tid < NB && sg[tid] != sg[0]) allsame = 0;   // benign race, all writes = 0
    __syncthreads();
    if (allsame) {
        if (tid < 64) {
            float s = 0.f;
#pragma unroll
            for (int n = 0; n < NB; ++n) s += hsf[n][tid];
            atomicAdd(&pool[sg[0] * 64 + tid], s);
        }
    } else if (valid) {
        int g = sg[nl];
        atomicAdd(&pool[g * 64 + 8 * l8 + 0], v0);
        atomicAdd(&pool[g * 64 + 8 * l8 + 1], v1);
        atomicAdd(&pool[g * 64 + 8 * l8 + 2], v2);
        atomicAdd(&pool[g * 64 + 8 * l8 + 3], v3);
        atomicAdd(&pool[g * 64 + 8 * l8 + 4], v4);
        atomicAdd(&pool[g * 64 + 8 * l8 + 5], v5);
        atomicAdd(&pool[g * 64 + 8 * l8 + 6], v6);
        atomicAdd(&pool[g * 64 + 8 * l8 + 7], v7);
    }
}

// ---------------------------------------------------------------- head
__global__ void head_kernel(const float* __restrict__ pool, const float* __restrict__ cnt,
                            const float* __restrict__ Wp, const float* __restrict__ bp,
                            float* __restrict__ out) {
    int g = blockIdx.x;
    int k = threadIdx.x;
    float v = pool[g * 64 + k] * Wp[k];
#pragma unroll
    for (int off = 32; off > 0; off >>= 1) v += __shfl_down(v, off);
    if (k == 0) out[g] = v / fmaxf(cnt[g], 1.0f) + bp[0];
}

extern "C" void kernel_launch(void* const* d_in, const int* in_sizes, int n_in,
                              void* d_out, int out_size, void* d_ws, size_t ws_size,
                              hipStream_t stream) {
    const float* x     = (const float*)d_in[0];
    const int*   ei    = (const int*)d_in[1];
    const int*   batch = (const int*)d_in[2];
    const float* W0 = (const float*)d_in[3];
    const float* b0 = (const float*)d_in[4];
    const float* W1 = (const float*)d_in[5];
    const float* b1 = (const float*)d_in[6];
    const float* W2 = (const float*)d_in[7];
    const float* b2 = (const float*)d_in[8];
    const float* Wp = (const float*)d_in[9];
    const float* bp = (const float*)d_in[10];
    float* out = (float*)d_out;

    __half* xws  = (__half*)d_ws;                      // N*64 fp16 (ping)
    __half* xwsB = xws + N_NODES * 64;                 // N*64 fp16 (pong)
    float* dinv    = (float*)(xwsB + N_NODES * 64);    // N
    int*   row_beg = (int*)(dinv + N_NODES);           // N
    int*   row_end = row_beg + N_NODES;                // N
    unsigned short* csr_src = (unsigned short*)(row_end + N_NODES);  // NPART*CAP u16
    int*   bucket  = (int*)(csr_src + NPART * CAP);    // NPART*CAP (u16 count is even -> 4B aligned)
    int*   pcount  = bucket + NPART * CAP;             // NPART (contiguous with pool+cnt)
    float* pool    = (float*)(pcount + NPART);         // 64*64
    float* cnt     = pool + 64 * 64;                   // 64

    (void)hipMemsetAsync(pcount, 0, (NPART + 64 * 64 + 64) * sizeof(int), stream);

    // ---- CSR build
    bucket_kernel<<<512, 256, 0, stream>>>(ei, pcount, bucket);
    csr_kernel<<<NPART, 256, 0, stream>>>(pcount, bucket, batch, row_beg, row_end, dinv,
                                          csr_src, cnt);

    // ---- layer 0 transform (fp32 input x)
    gemm64_kernel<<<1024, 256, 0, stream>>>(x, W0, dinv, xws);
    // ---- fused: layer-0 aggregate + relu + layer-1 transform
    fused_layer_kernel<<<NBLK, 256, 0, stream>>>(row_beg, row_end, csr_src, dinv,
                                                 xws, b0, W1, xwsB);
    // ---- fused: layer-1 aggregate + relu + layer-2 transform
    fused_layer_kernel<<<NBLK, 256, 0, stream>>>(row_beg, row_end, csr_src, dinv,
                                                 xwsB, b1, W2, xws);
    // ---- fused: layer-2 aggregate (no relu) + pool
    gather_pool_kernel<<<NBLK, 256, 0, stream>>>(row_beg, row_end, csr_src, dinv,
                                                 xws, b2, batch, pool);
    head_kernel<<<64, 64, 0, stream>>>(pool, cnt, Wp, bp, out);
}